// Round 7
// baseline (2846.168 us; speedup 1.0000x reference)
//
#include <hip/hip_runtime.h>
#include <stdint.h>

#define SEQ   256
#define BATCH 256
#define HID   1024
#define NCLS  10

// 128 WGs = 8 batch-groups (32 batch rows) x 16 hid-blocks (64 hid rows).
// Transposed recurrence: C = W^T (A-operand, regs) x h^T (B-operand, global).
// h fragments carry a per-word step TAG in the bf16 LSB -> consumers poll the
// data itself (no flags, no separate release/poll legs). Stores are plain
// cached full-line 16B/lane, published by a release-agent fence (wbl2).
#define NWG     128
#define THREADS 512
#define PLANEB  (32 * 16 * 64 * 16)   // 32 kstacks x 16 bfrags x 64 lanes x 16B

typedef __attribute__((ext_vector_type(8))) short bf16x8;
typedef __attribute__((ext_vector_type(4))) float f32x4;
typedef __attribute__((ext_vector_type(4))) unsigned int u32x4;

__device__ __forceinline__ unsigned short f2bf(float f) {
  unsigned u = __builtin_bit_cast(unsigned, f);
  u = (u + 0x7FFFu + ((u >> 16) & 1u)) >> 16;
  return (unsigned short)u;
}
__device__ __forceinline__ float bf2f(unsigned short h) {
  unsigned u = ((unsigned)h) << 16;
  return __builtin_bit_cast(float, u);
}
__device__ __forceinline__ float fast_tanh(float x) {
  float ax = __builtin_fabsf(x);
  float e = __expf(2.0f * ax);
  float t = 1.0f - 2.0f / (e + 1.0f);
  return __builtin_copysignf(t, x);
}
// step tag: alternates per plane reuse; 1 on first write of each plane so
// 0xAA/0x00 stale words (LSB=0) are rejected at t=1/t=2.
__device__ __forceinline__ unsigned tag_of(unsigned t) {
  return ((t >> 1) & 1u) ^ 1u;
}

__global__ __launch_bounds__(THREADS, 2) void rnn_tagged(
    const float* __restrict__ x, const float* __restrict__ Whx,
    const float* __restrict__ Whh, const float* __restrict__ Wph,
    const float* __restrict__ bh, const float* __restrict__ bp,
    float* __restrict__ out, unsigned char* __restrict__ ws)
{
  __shared__ f32x4 red[8][7][64];              // 56 KiB kt-split reduction
  __shared__ unsigned long long pkbuf[8][64];  // 4 KiB half-merge buffer

  const int tid  = threadIdx.x;
  const int lane = tid & 63;
  const int wv   = tid >> 6;          // 0..7
  const int l15  = lane & 15;
  const int q    = lane >> 4;

  const int gb = blockIdx.x >> 4;     // batch group 0..7 (rows gb*32..+31)
  const int s  = blockIdx.x & 15;     // hid block 0..15 (hid s*64..+63)

  unsigned char* p0 = ws;             // h^T plane 0 (512 KiB)
  unsigned char* p1 = ws + PLANEB;    // h^T plane 1

  // ---- prologue: this wave's W^T A-fragments (hi+lo) into registers (r6-proven)
  bf16x8 whi[4][4], wlo[4][4];
#pragma unroll
  for (int i = 0; i < 4; ++i) {
    const int ks = wv * 4 + i;
#pragma unroll
    for (int rt = 0; rt < 4; ++rt) {
      const int n = s * 64 + rt * 16 + l15;
#pragma unroll
      for (int j = 0; j < 8; ++j) {
        int k = ks * 32 + 4 * q + (j & 3) + 16 * (j >> 2);
        float w = Whh[(size_t)k * HID + n];
        unsigned short hi = f2bf(w);
        whi[i][rt][j] = (short)hi;
        wlo[i][rt][j] = (short)f2bf(w - bf2f(hi));
      }
    }
  }

  const int rt_o = wv >> 1, bt_o = wv & 1;     // owned C tile
  const int b_own = gb * 32 + bt_o * 16 + l15;
  const float* xrow = x + (size_t)b_own * SEQ;
  const float4 whx4 = *(const float4*)(Whx + s * 64 + rt_o * 16 + q * 4);
  const float4 bh4  = *(const float4*)(bh  + s * 64 + rt_o * 16 + q * 4);
  // storer fragment (waves 0,1,4,5): kstack = s*2+(wv>>2), bfrag = gb*2+(wv&1)
  const size_t soff = ((size_t)((s * 2 + (wv >> 2)) * 16 + gb * 2 + (wv & 1)) * 64 + lane) * 16;

  // ---- sequential time steps
  for (int t = 0; t < SEQ; ++t) {
    unsigned char* wp = (t & 1) ? p1 : p0;
    const unsigned char* rp = (t & 1) ? p0 : p1;    // plane of h_{t-1}
    const unsigned tauW = tag_of((unsigned)t);
    const float xb = xrow[t];

    f32x4 acc[4][2];
#pragma unroll
    for (int rt = 0; rt < 4; ++rt)
#pragma unroll
      for (int bt = 0; bt < 2; ++bt) acc[rt][bt] = (f32x4){0.f, 0.f, 0.f, 0.f};

    if (t > 0) {
      const unsigned tauR = tag_of((unsigned)(t - 1));
      u32x4 hf[4][2];
      // wave-autonomous tagged poll-load: data IS the flag
      for (;;) {
#pragma unroll
        for (int i = 0; i < 4; ++i)
#pragma unroll
          for (int bt = 0; bt < 2; ++bt)
            hf[i][bt] = *(const volatile u32x4*)
                (rp + ((size_t)((wv * 4 + i) * 16 + gb * 2 + bt) * 64 + lane) * 16);
        unsigned bad = 0;
#pragma unroll
        for (int i = 0; i < 4; ++i)
#pragma unroll
          for (int bt = 0; bt < 2; ++bt)
#pragma unroll
            for (int w = 0; w < 4; ++w) bad |= (hf[i][bt][w] ^ tauR) & 1u;
        if (__all((int)(bad == 0))) break;
        __builtin_amdgcn_s_sleep(1);
      }

#pragma unroll
      for (int i = 0; i < 4; ++i)
#pragma unroll
        for (int bt = 0; bt < 2; ++bt) {
          bf16x8 a = __builtin_bit_cast(bf16x8, hf[i][bt]);
#pragma unroll
          for (int rt = 0; rt < 4; ++rt) {
            acc[rt][bt] = __builtin_amdgcn_mfma_f32_16x16x32_bf16(whi[i][rt], a, acc[rt][bt], 0, 0, 0);
            acc[rt][bt] = __builtin_amdgcn_mfma_f32_16x16x32_bf16(wlo[i][rt], a, acc[rt][bt], 0, 0, 0);
          }
        }
    }

    // ---- cross-wave kt-split reduction (r6-proven, conflict-free)
#pragma unroll
    for (int T = 0; T < 8; ++T)
      if (T != wv)
        red[T][(wv > T) ? (wv - 1) : wv][lane] = acc[T >> 1][T & 1];
    __syncthreads();

    f32x4 ssum = acc[rt_o][bt_o];
#pragma unroll
    for (int pr = 0; pr < 7; ++pr) ssum += red[wv][pr][lane];

    // ---- epilogue: tanh, pack 4 bf16, tag both words
    const float v0 = fast_tanh(ssum[0] + xb * whx4.x + bh4.x);
    const float v1 = fast_tanh(ssum[1] + xb * whx4.y + bh4.y);
    const float v2 = fast_tanh(ssum[2] + xb * whx4.z + bh4.z);
    const float v3 = fast_tanh(ssum[3] + xb * whx4.w + bh4.w);
    unsigned w0 = ((unsigned)f2bf(v0) | ((unsigned)f2bf(v1) << 16));
    unsigned w1 = ((unsigned)f2bf(v2) | ((unsigned)f2bf(v3) << 16));
    w0 = (w0 & ~1u) | tauW;
    w1 = (w1 & ~1u) | tauW;
    unsigned long long pk = (unsigned long long)w0 | ((unsigned long long)w1 << 32);
    pkbuf[wv][lane] = pk;
    __syncthreads();

    // ---- waves 0,1,4,5 merge partner half -> one full-line 16B/lane plain store
    if (!(wv & 2)) {
      unsigned long long pk2 = pkbuf[wv | 2][lane];
      u32x4 st;
      st[0] = (unsigned)pk;  st[1] = (unsigned)(pk >> 32);
      st[2] = (unsigned)pk2; st[3] = (unsigned)(pk2 >> 32);
      *(u32x4*)(wp + soff) = st;
    }
    __syncthreads();   // drains storers' vmcnt (L2 ack)
    if (tid == 0)
      __builtin_amdgcn_fence(__ATOMIC_RELEASE, "agent");  // wbl2: publish to L3
  }

  // ---- final projection (one WG per batch-group): out = h_last @ Wph + bp
  if (s != 0) return;
  {
    const unsigned tauF = tag_of(255u);   // = 0
    u32x4 hf[4][2];
    for (;;) {
#pragma unroll
      for (int i = 0; i < 4; ++i)
#pragma unroll
        for (int bt = 0; bt < 2; ++bt)
          hf[i][bt] = *(const volatile u32x4*)
              (p1 + ((size_t)((wv * 4 + i) * 16 + gb * 2 + bt) * 64 + lane) * 16);
      unsigned bad = 0;
#pragma unroll
      for (int i = 0; i < 4; ++i)
#pragma unroll
        for (int bt = 0; bt < 2; ++bt)
#pragma unroll
          for (int w = 0; w < 4; ++w) bad |= (hf[i][bt][w] ^ tauF) & 1u;
      if (__all((int)(bad == 0))) break;
      __builtin_amdgcn_s_sleep(1);
    }

    float pr0[NCLS], pr1[NCLS];
#pragma unroll
    for (int c = 0; c < NCLS; ++c) { pr0[c] = 0.f; pr1[c] = 0.f; }
#pragma unroll
    for (int i = 0; i < 4; ++i) {
      const int ks = wv * 4 + i;
#pragma unroll
      for (int bt = 0; bt < 2; ++bt) {
#pragma unroll
        for (int w = 0; w < 4; ++w) {
          unsigned word = hf[i][bt][w];
#pragma unroll
          for (int h2 = 0; h2 < 2; ++h2) {
            int j = 2 * w + h2;
            int k = ks * 32 + 4 * q + (j & 3) + 16 * (j >> 2);
            float hv = bf2f((unsigned short)(h2 ? (word >> 16) : (word & 0xffffu)));
            const float* wrow = Wph + (size_t)k * NCLS;
#pragma unroll
            for (int c = 0; c < NCLS; ++c) {
              if (bt == 0) pr0[c] += hv * wrow[c];
              else         pr1[c] += hv * wrow[c];
            }
          }
        }
      }
    }
#pragma unroll
    for (int c = 0; c < NCLS; ++c) {
      pr0[c] += __shfl_xor(pr0[c], 16, 64); pr0[c] += __shfl_xor(pr0[c], 32, 64);
      pr1[c] += __shfl_xor(pr1[c], 16, 64); pr1[c] += __shfl_xor(pr1[c], 32, 64);
    }
    float* projl = (float*)&red[0][0][0];   // reuse LDS: [8 wv][2 bt][16 b][10 c]
    if (q == 0) {
#pragma unroll
      for (int c = 0; c < NCLS; ++c) {
        projl[((wv * 2 + 0) * 16 + l15) * NCLS + c] = pr0[c];
        projl[((wv * 2 + 1) * 16 + l15) * NCLS + c] = pr1[c];
      }
    }
    __syncthreads();
    if (tid < 32 * NCLS) {
      int bl = tid / NCLS, c = tid - bl * NCLS;
      float sum = bp[c];
#pragma unroll
      for (int w = 0; w < 8; ++w)
        sum += projl[((w * 2 + (bl >> 4)) * 16 + (bl & 15)) * NCLS + c];
      out[(size_t)(gb * 32 + bl) * NCLS + c] = sum;
    }
  }
}

extern "C" void kernel_launch(void* const* d_in, const int* in_sizes, int n_in,
                              void* d_out, int out_size, void* d_ws, size_t ws_size,
                              hipStream_t stream) {
  const float* x   = (const float*)d_in[0];
  const float* Whx = (const float*)d_in[1];
  const float* Whh = (const float*)d_in[2];
  const float* Wph = (const float*)d_in[3];
  const float* bh  = (const float*)d_in[4];
  const float* bp  = (const float*)d_in[5];

  // no memset needed: tags self-validate against poison/stale planes
  hipLaunchKernelGGL(rnn_tagged, dim3(NWG), dim3(THREADS), 0, stream,
                     x, Whx, Whh, Wph, bh, bp,
                     (float*)d_out, (unsigned char*)d_ws);
}

// Round 8
// 2187.595 us; speedup vs baseline: 1.3010x; 1.3010x over previous
//
#include <hip/hip_runtime.h>
#include <stdint.h>

#define SEQ   256
#define BATCH 256
#define HID   1024
#define NCLS  10

// 128 WGs = 8 batch-groups (32 batch rows) x 16 hid-blocks (64 hid rows).
// Transposed recurrence: C = W^T (A-operand, regs) x h^T (B-operand, global).
// h fragments carry a per-word step TAG in the bf16 LSB: consumers poll the
// data itself. Stores are write-through (volatile 16B/lane, full-line); NO
// fences, NO flag array, NO post-store barrier -- visibility self-validates,
// ABA closed by the intra-group dependency cycle (see r7/r8 analysis).
#define NWG     128
#define THREADS 512
#define PLANEB  (32 * 16 * 64 * 16)   // 32 kstacks x 16 bfrags x 64 lanes x 16B

typedef __attribute__((ext_vector_type(8))) short bf16x8;
typedef __attribute__((ext_vector_type(4))) float f32x4;
typedef __attribute__((ext_vector_type(4))) unsigned int u32x4;

__device__ __forceinline__ unsigned short f2bf(float f) {
  unsigned u = __builtin_bit_cast(unsigned, f);
  u = (u + 0x7FFFu + ((u >> 16) & 1u)) >> 16;
  return (unsigned short)u;
}
__device__ __forceinline__ float bf2f(unsigned short h) {
  unsigned u = ((unsigned)h) << 16;
  return __builtin_bit_cast(float, u);
}
__device__ __forceinline__ float fast_tanh(float x) {
  float ax = __builtin_fabsf(x);
  float e = __expf(2.0f * ax);
  float t = 1.0f - 2.0f / (e + 1.0f);
  return __builtin_copysignf(t, x);
}
// step tag: plane p is written at t with p==(t&1); tags alternate 1,0,1,0 per
// plane-write; first write of each plane has tag 1 so 0xAA / stale-replay data
// (tag 0) is rejected at the first read of each plane.
__device__ __forceinline__ unsigned tag_of(unsigned t) {
  return ((t >> 1) & 1u) ^ 1u;
}

__global__ __launch_bounds__(THREADS, 2) void rnn_wt_tagged(
    const float* __restrict__ x, const float* __restrict__ Whx,
    const float* __restrict__ Whh, const float* __restrict__ Wph,
    const float* __restrict__ bh, const float* __restrict__ bp,
    float* __restrict__ out, unsigned char* __restrict__ ws)
{
  __shared__ f32x4 red[8][7][64];              // 56 KiB kt-split reduction
  __shared__ unsigned long long pkbuf[8][64];  // 4 KiB half-merge buffer

  const int tid  = threadIdx.x;
  const int lane = tid & 63;
  const int wv   = tid >> 6;          // 0..7
  const int l15  = lane & 15;
  const int q    = lane >> 4;

  const int gb = blockIdx.x >> 4;     // batch group 0..7 (rows gb*32..+31)
  const int s  = blockIdx.x & 15;     // hid block 0..15 (hid s*64..+63)

  unsigned char* p0 = ws;             // h^T plane 0 (512 KiB)
  unsigned char* p1 = ws + PLANEB;    // h^T plane 1

  // ---- prologue: this wave's W^T A-fragments (hi+lo) into registers (r6/r7-proven)
  bf16x8 whi[4][4], wlo[4][4];
#pragma unroll
  for (int i = 0; i < 4; ++i) {
    const int ks = wv * 4 + i;
#pragma unroll
    for (int rt = 0; rt < 4; ++rt) {
      const int n = s * 64 + rt * 16 + l15;
#pragma unroll
      for (int j = 0; j < 8; ++j) {
        int k = ks * 32 + 4 * q + (j & 3) + 16 * (j >> 2);
        float w = Whh[(size_t)k * HID + n];
        unsigned short hi = f2bf(w);
        whi[i][rt][j] = (short)hi;
        wlo[i][rt][j] = (short)f2bf(w - bf2f(hi));
      }
    }
  }

  const int rt_o = wv >> 1, bt_o = wv & 1;     // owned C tile
  const int b_own = gb * 32 + bt_o * 16 + l15;
  const float* xrow = x + (size_t)b_own * SEQ;
  const float4 whx4 = *(const float4*)(Whx + s * 64 + rt_o * 16 + q * 4);
  const float4 bh4  = *(const float4*)(bh  + s * 64 + rt_o * 16 + q * 4);
  // storer fragment (waves 0,1,4,5): kstack = s*2+(wv>>2), bfrag = gb*2+(wv&1)
  const size_t soff = ((size_t)((s * 2 + (wv >> 2)) * 16 + gb * 2 + (wv & 1)) * 64 + lane) * 16;
  volatile u32x4* st0 = (volatile u32x4*)(p0 + soff);
  volatile u32x4* st1 = (volatile u32x4*)(p1 + soff);

  // per-wave poll/load addresses (8 fragments per plane)
  const volatile u32x4* ld0[4][2];
  const volatile u32x4* ld1[4][2];
#pragma unroll
  for (int i = 0; i < 4; ++i)
#pragma unroll
    for (int bt = 0; bt < 2; ++bt) {
      size_t o = ((size_t)((wv * 4 + i) * 16 + gb * 2 + bt) * 64 + lane) * 16;
      ld0[i][bt] = (const volatile u32x4*)(p0 + o);
      ld1[i][bt] = (const volatile u32x4*)(p1 + o);
    }

  // ---- sequential time steps
  for (int t = 0; t < SEQ; ++t) {
    const unsigned tauW = tag_of((unsigned)t);
    const float xb = xrow[t];

    f32x4 acc[4][2];
#pragma unroll
    for (int rt = 0; rt < 4; ++rt)
#pragma unroll
      for (int bt = 0; bt < 2; ++bt) acc[rt][bt] = (f32x4){0.f, 0.f, 0.f, 0.f};

    if (t > 0) {
      const unsigned tauR = tag_of((unsigned)(t - 1));
      const bool rdp0 = ((t & 1) == 1);          // step t reads plane (t-1)&1
      u32x4 hf[4][2];
      // wave-autonomous tagged poll-load: the data IS the flag
      for (;;) {
#pragma unroll
        for (int i = 0; i < 4; ++i)
#pragma unroll
          for (int bt = 0; bt < 2; ++bt)
            hf[i][bt] = rdp0 ? *ld0[i][bt] : *ld1[i][bt];
        unsigned bad = 0;
#pragma unroll
        for (int i = 0; i < 4; ++i)
#pragma unroll
          for (int bt = 0; bt < 2; ++bt)
#pragma unroll
            for (int w = 0; w < 4; ++w) bad |= (hf[i][bt][w] ^ tauR) & 1u;
        if (__all((int)(bad == 0))) break;
        __builtin_amdgcn_s_sleep(2);
      }

#pragma unroll
      for (int i = 0; i < 4; ++i)
#pragma unroll
        for (int bt = 0; bt < 2; ++bt) {
          bf16x8 a = __builtin_bit_cast(bf16x8, hf[i][bt]);
#pragma unroll
          for (int rt = 0; rt < 4; ++rt) {
            acc[rt][bt] = __builtin_amdgcn_mfma_f32_16x16x32_bf16(whi[i][rt], a, acc[rt][bt], 0, 0, 0);
            acc[rt][bt] = __builtin_amdgcn_mfma_f32_16x16x32_bf16(wlo[i][rt], a, acc[rt][bt], 0, 0, 0);
          }
        }
    }

    // ---- cross-wave kt-split reduction (conflict-free, r6-proven)
#pragma unroll
    for (int T = 0; T < 8; ++T)
      if (T != wv)
        red[T][(wv > T) ? (wv - 1) : wv][lane] = acc[T >> 1][T & 1];
    __syncthreads();

    f32x4 ssum = acc[rt_o][bt_o];
#pragma unroll
    for (int pr = 0; pr < 7; ++pr) ssum += red[wv][pr][lane];

    // ---- epilogue: tanh, pack 4 bf16, tag every 32-bit word
    const float v0 = fast_tanh(ssum[0] + xb * whx4.x + bh4.x);
    const float v1 = fast_tanh(ssum[1] + xb * whx4.y + bh4.y);
    const float v2 = fast_tanh(ssum[2] + xb * whx4.z + bh4.z);
    const float v3 = fast_tanh(ssum[3] + xb * whx4.w + bh4.w);
    unsigned w0 = ((unsigned)f2bf(v0) | ((unsigned)f2bf(v1) << 16));
    unsigned w1 = ((unsigned)f2bf(v2) | ((unsigned)f2bf(v3) << 16));
    w0 = (w0 & ~1u) | tauW;
    w1 = (w1 & ~1u) | tauW;
    unsigned long long pk = (unsigned long long)w0 | ((unsigned long long)w1 << 32);
    pkbuf[wv][lane] = pk;
    __syncthreads();

    // ---- waves 0,1,4,5: merge partner half, ONE fire-and-forget 16B
    // write-through store (full 64B lines across the wave). No drain, no fence.
    if (!(wv & 2)) {
      unsigned long long pk2 = pkbuf[wv | 2][lane];
      u32x4 st;
      st[0] = (unsigned)pk;  st[1] = (unsigned)(pk >> 32);
      st[2] = (unsigned)pk2; st[3] = (unsigned)(pk2 >> 32);
      if (t & 1) *st1 = st; else *st0 = st;
    }
  }

  // ---- final projection (one WG per batch-group): out = h_last @ Wph + bp
  if (s != 0) return;
  {
    const unsigned tauF = tag_of(255u);   // = 0 (t=253's tag is 1 -> rejected)
    u32x4 hf[4][2];
    for (;;) {
#pragma unroll
      for (int i = 0; i < 4; ++i)
#pragma unroll
        for (int bt = 0; bt < 2; ++bt)
          hf[i][bt] = *ld1[i][bt];
      unsigned bad = 0;
#pragma unroll
      for (int i = 0; i < 4; ++i)
#pragma unroll
        for (int bt = 0; bt < 2; ++bt)
#pragma unroll
          for (int w = 0; w < 4; ++w) bad |= (hf[i][bt][w] ^ tauF) & 1u;
      if (__all((int)(bad == 0))) break;
      __builtin_amdgcn_s_sleep(2);
    }

    float pr0[NCLS], pr1[NCLS];
#pragma unroll
    for (int c = 0; c < NCLS; ++c) { pr0[c] = 0.f; pr1[c] = 0.f; }
#pragma unroll
    for (int i = 0; i < 4; ++i) {
      const int ks = wv * 4 + i;
#pragma unroll
      for (int bt = 0; bt < 2; ++bt) {
#pragma unroll
        for (int w = 0; w < 4; ++w) {
          unsigned word = hf[i][bt][w];
#pragma unroll
          for (int h2 = 0; h2 < 2; ++h2) {
            int j = 2 * w + h2;
            int k = ks * 32 + 4 * q + (j & 3) + 16 * (j >> 2);
            float hv = bf2f((unsigned short)(h2 ? (word >> 16) : (word & 0xffffu)));
            const float* wrow = Wph + (size_t)k * NCLS;
#pragma unroll
            for (int c = 0; c < NCLS; ++c) {
              if (bt == 0) pr0[c] += hv * wrow[c];
              else         pr1[c] += hv * wrow[c];
            }
          }
        }
      }
    }
#pragma unroll
    for (int c = 0; c < NCLS; ++c) {
      pr0[c] += __shfl_xor(pr0[c], 16, 64); pr0[c] += __shfl_xor(pr0[c], 32, 64);
      pr1[c] += __shfl_xor(pr1[c], 16, 64); pr1[c] += __shfl_xor(pr1[c], 32, 64);
    }
    float* projl = (float*)&red[0][0][0];   // reuse LDS: [8 wv][2 bt][16 b][10 c]
    if (q == 0) {
#pragma unroll
      for (int c = 0; c < NCLS; ++c) {
        projl[((wv * 2 + 0) * 16 + l15) * NCLS + c] = pr0[c];
        projl[((wv * 2 + 1) * 16 + l15) * NCLS + c] = pr1[c];
      }
    }
    __syncthreads();
    if (tid < 32 * NCLS) {
      int bl = tid / NCLS, c = tid - bl * NCLS;
      float sum = bp[c];
#pragma unroll
      for (int w = 0; w < 8; ++w)
        sum += projl[((w * 2 + (bl >> 4)) * 16 + (bl & 15)) * NCLS + c];
      out[(size_t)(gb * 32 + bl) * NCLS + c] = sum;
    }
  }
}

extern "C" void kernel_launch(void* const* d_in, const int* in_sizes, int n_in,
                              void* d_out, int out_size, void* d_ws, size_t ws_size,
                              hipStream_t stream) {
  const float* x   = (const float*)d_in[0];
  const float* Whx = (const float*)d_in[1];
  const float* Whh = (const float*)d_in[2];
  const float* Wph = (const float*)d_in[3];
  const float* bh  = (const float*)d_in[4];
  const float* bp  = (const float*)d_in[5];

  // no memset: tags self-validate against poison / stale replay data
  hipLaunchKernelGGL(rnn_wt_tagged, dim3(NWG), dim3(THREADS), 0, stream,
                     x, Whx, Whh, Wph, bh, bp,
                     (float*)d_out, (unsigned char*)d_ws);
}

// Round 10
// 1497.792 us; speedup vs baseline: 1.9002x; 1.4605x over previous
//
#include <hip/hip_runtime.h>
#include <stdint.h>

#define SEQ   256
#define BATCH 256
#define HID   1024
#define NCLS  10

// 128 WGs = 8 batch-groups (32 batch rows) x 16 hid-blocks (64 hid rows).
// Transposed recurrence: C = W^T (A-operand, regs) x h^T (B-operand, global).
// h fragments carry a per-word step TAG in the bf16 LSB: consumers poll the
// data itself (r7/r8-proven). r9/r10: all cross-WG loads are BATCHED
// inline-asm (one s_waitcnt for 8 loads), two-phase poll (4B tag probe,
// then one 16B reload + verify). r10 fixes gfx950 operand order:
// "off offset:N sc0 sc1" (offset BEFORE cache flags).
#define NWG     128
#define THREADS 512
#define PLANEB  (32 * 16 * 64 * 16)   // 32 kstacks x 16 bfrags x 64 lanes x 16B

typedef __attribute__((ext_vector_type(8))) short bf16x8;
typedef __attribute__((ext_vector_type(4))) float f32x4;
typedef __attribute__((ext_vector_type(4))) unsigned int u32x4;

__device__ __forceinline__ unsigned short f2bf(float f) {
  unsigned u = __builtin_bit_cast(unsigned, f);
  u = (u + 0x7FFFu + ((u >> 16) & 1u)) >> 16;
  return (unsigned short)u;
}
__device__ __forceinline__ float bf2f(unsigned short h) {
  unsigned u = ((unsigned)h) << 16;
  return __builtin_bit_cast(float, u);
}
__device__ __forceinline__ float fast_tanh(float x) {
  float ax = __builtin_fabsf(x);
  float e = __expf(2.0f * ax);
  float t = 1.0f - 2.0f / (e + 1.0f);
  return __builtin_copysignf(t, x);
}
// tag alternates per plane reuse; first write of each plane is 1, so 0xAA
// poison / replay-stale words (LSB 0) are rejected.
__device__ __forceinline__ unsigned tag_of(unsigned t) {
  return ((t >> 1) & 1u) ^ 1u;
}

__global__ __launch_bounds__(THREADS, 2) void rnn_asmpoll(
    const float* __restrict__ x, const float* __restrict__ Whx,
    const float* __restrict__ Whh, const float* __restrict__ Wph,
    const float* __restrict__ bh, const float* __restrict__ bp,
    float* __restrict__ out, unsigned char* __restrict__ ws)
{
  __shared__ f32x4 red[8][7][64];              // 56 KiB kt-split reduction
  __shared__ unsigned long long pkbuf[8][64];  // 4 KiB half-merge buffer

  const int tid  = threadIdx.x;
  const int lane = tid & 63;
  const int wv   = tid >> 6;          // 0..7
  const int l15  = lane & 15;
  const int q    = lane >> 4;

  const int gb = blockIdx.x >> 4;     // batch group 0..7 (rows gb*32..+31)
  const int s  = blockIdx.x & 15;     // hid block 0..15 (hid s*64..+63)

  unsigned char* p0 = ws;             // h^T plane 0 (512 KiB)
  unsigned char* p1 = ws + PLANEB;    // h^T plane 1

  // ---- prologue: this wave's W^T A-fragments (hi+lo) into registers (r6-r8 proven)
  bf16x8 whi[4][4], wlo[4][4];
#pragma unroll
  for (int i = 0; i < 4; ++i) {
    const int ks = wv * 4 + i;
#pragma unroll
    for (int rt = 0; rt < 4; ++rt) {
      const int n = s * 64 + rt * 16 + l15;
#pragma unroll
      for (int j = 0; j < 8; ++j) {
        int k = ks * 32 + 4 * q + (j & 3) + 16 * (j >> 2);
        float w = Whh[(size_t)k * HID + n];
        unsigned short hi = f2bf(w);
        whi[i][rt][j] = (short)hi;
        wlo[i][rt][j] = (short)f2bf(w - bf2f(hi));
      }
    }
  }

  const int rt_o = wv >> 1, bt_o = wv & 1;     // owned C tile
  const int b_own = gb * 32 + bt_o * 16 + l15;
  const float* xrow = x + (size_t)b_own * SEQ;
  const float4 whx4 = *(const float4*)(Whx + s * 64 + rt_o * 16 + q * 4);
  const float4 bh4  = *(const float4*)(bh  + s * 64 + rt_o * 16 + q * 4);
  // storer fragment (waves 0,1,4,5): kstack = s*2+(wv>>2), bfrag = gb*2+(wv&1)
  const size_t soff = ((size_t)((s * 2 + (wv >> 2)) * 16 + gb * 2 + (wv & 1)) * 64 + lane) * 16;
  volatile u32x4* st0 = (volatile u32x4*)(p0 + soff);
  volatile u32x4* st1 = (volatile u32x4*)(p1 + soff);

  // per-wave load bases: fragment (i, bt) at base_i + bt*1024 (imm offset)
  const size_t oA0 = ((size_t)((wv * 4 + 0) * 16 + gb * 2) * 64 + lane) * 16;
  const size_t oA1 = ((size_t)((wv * 4 + 1) * 16 + gb * 2) * 64 + lane) * 16;
  const size_t oA2 = ((size_t)((wv * 4 + 2) * 16 + gb * 2) * 64 + lane) * 16;
  const size_t oA3 = ((size_t)((wv * 4 + 3) * 16 + gb * 2) * 64 + lane) * 16;

  // ---- sequential time steps
  for (int t = 0; t < SEQ; ++t) {
    const unsigned tauW = tag_of((unsigned)t);
    const float xb = xrow[t];

    f32x4 acc[4][2];
#pragma unroll
    for (int rt = 0; rt < 4; ++rt)
#pragma unroll
      for (int bt = 0; bt < 2; ++bt) acc[rt][bt] = (f32x4){0.f, 0.f, 0.f, 0.f};

    if (t > 0) {
      const unsigned tauR = tag_of((unsigned)(t - 1));
      const unsigned char* rp = (t & 1) ? p0 : p1;     // plane of h_{t-1}
      const unsigned char* b0 = rp + oA0;
      const unsigned char* b1 = rp + oA1;
      const unsigned char* b2 = rp + oA2;
      const unsigned char* b3 = rp + oA3;
      u32x4 f0, f1, f2, f3, f4, f5, f6, f7;

      for (;;) {
        // ---- phase A: 8x4B tag probe, ONE waitcnt (one MALL round trip)
        unsigned s0, s1, s2, s3, s4, s5, s6, s7;
        asm volatile(
          "global_load_dword %0, %8, off sc0 sc1\n\t"
          "global_load_dword %1, %8, off offset:1024 sc0 sc1\n\t"
          "global_load_dword %2, %9, off sc0 sc1\n\t"
          "global_load_dword %3, %9, off offset:1024 sc0 sc1\n\t"
          "global_load_dword %4, %10, off sc0 sc1\n\t"
          "global_load_dword %5, %10, off offset:1024 sc0 sc1\n\t"
          "global_load_dword %6, %11, off sc0 sc1\n\t"
          "global_load_dword %7, %11, off offset:1024 sc0 sc1\n\t"
          "s_waitcnt vmcnt(0)"
          : "=&v"(s0), "=&v"(s1), "=&v"(s2), "=&v"(s3),
            "=&v"(s4), "=&v"(s5), "=&v"(s6), "=&v"(s7)
          : "v"(b0), "v"(b1), "v"(b2), "v"(b3)
          : "memory");
        __builtin_amdgcn_sched_barrier(0);
        unsigned bad = ((s0 ^ tauR) | (s1 ^ tauR) | (s2 ^ tauR) | (s3 ^ tauR) |
                        (s4 ^ tauR) | (s5 ^ tauR) | (s6 ^ tauR) | (s7 ^ tauR)) & 1u;
        if (!__all((int)(bad == 0))) { __builtin_amdgcn_s_sleep(1); continue; }

        // ---- phase B: full 8x16B reload + verify (safe: plane can't be
        // overwritten until our own WG completes t+1, which needs this read)
        asm volatile(
          "global_load_dwordx4 %0, %8, off sc0 sc1\n\t"
          "global_load_dwordx4 %1, %8, off offset:1024 sc0 sc1\n\t"
          "global_load_dwordx4 %2, %9, off sc0 sc1\n\t"
          "global_load_dwordx4 %3, %9, off offset:1024 sc0 sc1\n\t"
          "global_load_dwordx4 %4, %10, off sc0 sc1\n\t"
          "global_load_dwordx4 %5, %10, off offset:1024 sc0 sc1\n\t"
          "global_load_dwordx4 %6, %11, off sc0 sc1\n\t"
          "global_load_dwordx4 %7, %11, off offset:1024 sc0 sc1\n\t"
          "s_waitcnt vmcnt(0)"
          : "=&v"(f0), "=&v"(f1), "=&v"(f2), "=&v"(f3),
            "=&v"(f4), "=&v"(f5), "=&v"(f6), "=&v"(f7)
          : "v"(b0), "v"(b1), "v"(b2), "v"(b3)
          : "memory");
        __builtin_amdgcn_sched_barrier(0);
        unsigned vb = ((f0[0] ^ tauR) | (f0[1] ^ tauR) | (f0[2] ^ tauR) | (f0[3] ^ tauR) |
                       (f1[0] ^ tauR) | (f1[1] ^ tauR) | (f1[2] ^ tauR) | (f1[3] ^ tauR) |
                       (f2[0] ^ tauR) | (f2[1] ^ tauR) | (f2[2] ^ tauR) | (f2[3] ^ tauR) |
                       (f3[0] ^ tauR) | (f3[1] ^ tauR) | (f3[2] ^ tauR) | (f3[3] ^ tauR) |
                       (f4[0] ^ tauR) | (f4[1] ^ tauR) | (f4[2] ^ tauR) | (f4[3] ^ tauR) |
                       (f5[0] ^ tauR) | (f5[1] ^ tauR) | (f5[2] ^ tauR) | (f5[3] ^ tauR) |
                       (f6[0] ^ tauR) | (f6[1] ^ tauR) | (f6[2] ^ tauR) | (f6[3] ^ tauR) |
                       (f7[0] ^ tauR) | (f7[1] ^ tauR) | (f7[2] ^ tauR) | (f7[3] ^ tauR)) & 1u;
        if (__all((int)(vb == 0))) break;
        __builtin_amdgcn_s_sleep(1);
      }

      // ---- 64 MFMAs (hi+lo), fragment (i, bt) = f[2i+bt]
#define MSTEP(F, I, BT)                                                        \
      { bf16x8 a_ = __builtin_bit_cast(bf16x8, F);                             \
        acc[0][BT] = __builtin_amdgcn_mfma_f32_16x16x32_bf16(whi[I][0], a_, acc[0][BT], 0, 0, 0); \
        acc[0][BT] = __builtin_amdgcn_mfma_f32_16x16x32_bf16(wlo[I][0], a_, acc[0][BT], 0, 0, 0); \
        acc[1][BT] = __builtin_amdgcn_mfma_f32_16x16x32_bf16(whi[I][1], a_, acc[1][BT], 0, 0, 0); \
        acc[1][BT] = __builtin_amdgcn_mfma_f32_16x16x32_bf16(wlo[I][1], a_, acc[1][BT], 0, 0, 0); \
        acc[2][BT] = __builtin_amdgcn_mfma_f32_16x16x32_bf16(whi[I][2], a_, acc[2][BT], 0, 0, 0); \
        acc[2][BT] = __builtin_amdgcn_mfma_f32_16x16x32_bf16(wlo[I][2], a_, acc[2][BT], 0, 0, 0); \
        acc[3][BT] = __builtin_amdgcn_mfma_f32_16x16x32_bf16(whi[I][3], a_, acc[3][BT], 0, 0, 0); \
        acc[3][BT] = __builtin_amdgcn_mfma_f32_16x16x32_bf16(wlo[I][3], a_, acc[3][BT], 0, 0, 0); }
      MSTEP(f0, 0, 0) MSTEP(f1, 0, 1) MSTEP(f2, 1, 0) MSTEP(f3, 1, 1)
      MSTEP(f4, 2, 0) MSTEP(f5, 2, 1) MSTEP(f6, 3, 0) MSTEP(f7, 3, 1)
#undef MSTEP
    }

    // ---- cross-wave kt-split reduction (conflict-free, r6-proven)
#pragma unroll
    for (int T = 0; T < 8; ++T)
      if (T != wv)
        red[T][(wv > T) ? (wv - 1) : wv][lane] = acc[T >> 1][T & 1];
    __syncthreads();

    f32x4 ssum = acc[rt_o][bt_o];
#pragma unroll
    for (int pr = 0; pr < 7; ++pr) ssum += red[wv][pr][lane];

    // ---- epilogue: tanh, pack 4 bf16, tag every 32-bit word
    const float v0 = fast_tanh(ssum[0] + xb * whx4.x + bh4.x);
    const float v1 = fast_tanh(ssum[1] + xb * whx4.y + bh4.y);
    const float v2 = fast_tanh(ssum[2] + xb * whx4.z + bh4.z);
    const float v3 = fast_tanh(ssum[3] + xb * whx4.w + bh4.w);
    unsigned w0 = ((unsigned)f2bf(v0) | ((unsigned)f2bf(v1) << 16));
    unsigned w1 = ((unsigned)f2bf(v2) | ((unsigned)f2bf(v3) << 16));
    w0 = (w0 & ~1u) | tauW;
    w1 = (w1 & ~1u) | tauW;
    unsigned long long pk = (unsigned long long)w0 | ((unsigned long long)w1 << 32);
    pkbuf[wv][lane] = pk;
    __syncthreads();

    // ---- waves 0,1,4,5: merge partner half, one fire-and-forget full-line
    // 16B write-through store (r8-proven visibility; no drain, no fence)
    if (!(wv & 2)) {
      unsigned long long pk2 = pkbuf[wv | 2][lane];
      u32x4 st;
      st[0] = (unsigned)pk;  st[1] = (unsigned)(pk >> 32);
      st[2] = (unsigned)pk2; st[3] = (unsigned)(pk2 >> 32);
      if (t & 1) *st1 = st; else *st0 = st;
    }
  }

  // ---- final projection (one WG per batch-group): out = h_last @ Wph + bp
  if (s != 0) return;
  {
    const unsigned tauF = tag_of(255u);   // = 0
    u32x4 hf[4][2];
    for (;;) {
#pragma unroll
      for (int i = 0; i < 4; ++i)
#pragma unroll
        for (int bt = 0; bt < 2; ++bt)
          hf[i][bt] = *(const volatile u32x4*)
              (p1 + ((size_t)((wv * 4 + i) * 16 + gb * 2 + bt) * 64 + lane) * 16);
      unsigned bad = 0;
#pragma unroll
      for (int i = 0; i < 4; ++i)
#pragma unroll
        for (int bt = 0; bt < 2; ++bt)
#pragma unroll
          for (int w = 0; w < 4; ++w) bad |= (hf[i][bt][w] ^ tauF) & 1u;
      if (__all((int)(bad == 0))) break;
      __builtin_amdgcn_s_sleep(2);
    }

    float pr0[NCLS], pr1[NCLS];
#pragma unroll
    for (int c = 0; c < NCLS; ++c) { pr0[c] = 0.f; pr1[c] = 0.f; }
#pragma unroll
    for (int i = 0; i < 4; ++i) {
      const int ks = wv * 4 + i;
#pragma unroll
      for (int bt = 0; bt < 2; ++bt) {
#pragma unroll
        for (int w = 0; w < 4; ++w) {
          unsigned word = hf[i][bt][w];
#pragma unroll
          for (int h2 = 0; h2 < 2; ++h2) {
            int j = 2 * w + h2;
            int k = ks * 32 + 4 * q + (j & 3) + 16 * (j >> 2);
            float hv = bf2f((unsigned short)(h2 ? (word >> 16) : (word & 0xffffu)));
            const float* wrow = Wph + (size_t)k * NCLS;
#pragma unroll
            for (int c = 0; c < NCLS; ++c) {
              if (bt == 0) pr0[c] += hv * wrow[c];
              else         pr1[c] += hv * wrow[c];
            }
          }
        }
      }
    }
#pragma unroll
    for (int c = 0; c < NCLS; ++c) {
      pr0[c] += __shfl_xor(pr0[c], 16, 64); pr0[c] += __shfl_xor(pr0[c], 32, 64);
      pr1[c] += __shfl_xor(pr1[c], 16, 64); pr1[c] += __shfl_xor(pr1[c], 32, 64);
    }
    float* projl = (float*)&red[0][0][0];   // reuse LDS: [8 wv][2 bt][16 b][10 c]
    if (q == 0) {
#pragma unroll
      for (int c = 0; c < NCLS; ++c) {
        projl[((wv * 2 + 0) * 16 + l15) * NCLS + c] = pr0[c];
        projl[((wv * 2 + 1) * 16 + l15) * NCLS + c] = pr1[c];
      }
    }
    __syncthreads();
    if (tid < 32 * NCLS) {
      int bl = tid / NCLS, c = tid - bl * NCLS;
      float sum = bp[c];
#pragma unroll
      for (int w = 0; w < 8; ++w)
        sum += projl[((w * 2 + (bl >> 4)) * 16 + (bl & 15)) * NCLS + c];
      out[(size_t)(gb * 32 + bl) * NCLS + c] = sum;
    }
  }
}

extern "C" void kernel_launch(void* const* d_in, const int* in_sizes, int n_in,
                              void* d_out, int out_size, void* d_ws, size_t ws_size,
                              hipStream_t stream) {
  const float* x   = (const float*)d_in[0];
  const float* Whx = (const float*)d_in[1];
  const float* Whh = (const float*)d_in[2];
  const float* Wph = (const float*)d_in[3];
  const float* bh  = (const float*)d_in[4];
  const float* bp  = (const float*)d_in[5];

  // no memset: tags self-validate against poison / stale replay data
  hipLaunchKernelGGL(rnn_asmpoll, dim3(NWG), dim3(THREADS), 0, stream,
                     x, Whx, Whh, Wph, bh, bp,
                     (float*)d_out, (unsigned char*)d_ws);
}

// Round 11
// 1272.669 us; speedup vs baseline: 2.2364x; 1.1769x over previous
//
#include <hip/hip_runtime.h>
#include <stdint.h>

#define SEQ   256
#define BATCH 256
#define HID   1024
#define NCLS  10

// 128 WGs = 8 batch-groups (32 batch rows) x 16 hid-blocks (64 hid rows).
// Transposed recurrence: C = W^T (A-operand, regs) x h^T (B-operand, global).
// h fragments carry a per-word step TAG in the bf16 LSB (r7-r10 proven).
// r11: SINGLE-phase poll (full 16B loads + 32-bit-tag verify ARE the poll;
// one fabric RT instead of probe+reload) and SINGLE barrier per step
// (fragment-owner waves 0-3 get both 8B halves from the kt-reduction;
// red[] double-buffered by t&1 closes the WAR hazard structurally).
#define NWG     128
#define THREADS 512
#define PLANEB  (32 * 16 * 64 * 16)   // 32 kstacks x 16 bfrags x 64 lanes x 16B

typedef __attribute__((ext_vector_type(8))) short bf16x8;
typedef __attribute__((ext_vector_type(4))) float f32x4;
typedef __attribute__((ext_vector_type(4))) unsigned int u32x4;

__device__ __forceinline__ unsigned short f2bf(float f) {
  unsigned u = __builtin_bit_cast(unsigned, f);
  u = (u + 0x7FFFu + ((u >> 16) & 1u)) >> 16;
  return (unsigned short)u;
}
__device__ __forceinline__ float bf2f(unsigned short h) {
  unsigned u = ((unsigned)h) << 16;
  return __builtin_bit_cast(float, u);
}
__device__ __forceinline__ float fast_tanh(float x) {
  float ax = __builtin_fabsf(x);
  float e = __expf(2.0f * ax);
  float t = 1.0f - 2.0f / (e + 1.0f);
  return __builtin_copysignf(t, x);
}
// tag alternates per plane reuse; first write of each plane is 1, so 0xAA
// poison / replay-stale words (LSB 0) are rejected (r8/r10 proven).
__device__ __forceinline__ unsigned tag_of(unsigned t) {
  return ((t >> 1) & 1u) ^ 1u;
}

__global__ __launch_bounds__(THREADS, 1) void rnn_onebar(
    const float* __restrict__ x, const float* __restrict__ Whx,
    const float* __restrict__ Whh, const float* __restrict__ Wph,
    const float* __restrict__ bh, const float* __restrict__ bp,
    float* __restrict__ out, unsigned char* __restrict__ ws)
{
  // double-buffered kt-split reduction: [buf][rt][bt][producer slot][lane]
  __shared__ f32x4 red[2][4][2][7][64];        // 112 KiB

  const int tid  = threadIdx.x;
  const int lane = tid & 63;
  const int wv   = tid >> 6;          // 0..7
  const int l15  = lane & 15;
  const int q    = lane >> 4;

  const int gb = blockIdx.x >> 4;     // batch group 0..7 (rows gb*32..+31)
  const int s  = blockIdx.x & 15;     // hid block 0..15 (hid s*64..+63)

  unsigned char* p0 = ws;             // h^T plane 0 (512 KiB)
  unsigned char* p1 = ws + PLANEB;    // h^T plane 1

  // ---- prologue: this wave's W^T A-fragments (hi+lo) into registers (r6-r10)
  bf16x8 whi[4][4], wlo[4][4];
#pragma unroll
  for (int i = 0; i < 4; ++i) {
    const int ks = wv * 4 + i;
#pragma unroll
    for (int rt = 0; rt < 4; ++rt) {
      const int n = s * 64 + rt * 16 + l15;
#pragma unroll
      for (int j = 0; j < 8; ++j) {
        int k = ks * 32 + 4 * q + (j & 3) + 16 * (j >> 2);
        float w = Whh[(size_t)k * HID + n];
        unsigned short hi = f2bf(w);
        whi[i][rt][j] = (short)hi;
        wlo[i][rt][j] = (short)f2bf(w - bf2f(hi));
      }
    }
  }

  // owner mapping: tile (rt,bt) is owned by wave o=(rt&2)|bt; owners are waves
  // 0..3, each owning tiles {2u, 2u+1} x bt with u=wv>>1, bt=wv&1 -> one full
  // 16B fragment (kstack s*2+u, bfrag gb*2+bt): low 8B = tile 2u, high = 2u+1.
  const int u_o  = wv >> 1, bt_oo = wv & 1;    // owner coords (valid for wv<4)
  const int b_own = gb * 32 + bt_oo * 16 + l15;
  const float* xrow = x + (size_t)b_own * SEQ;
  float4 whxA, whxB, bhA, bhB;
  whxA = *(const float4*)(Whx + s * 64 + (2 * u_o) * 16 + q * 4);
  whxB = *(const float4*)(Whx + s * 64 + (2 * u_o + 1) * 16 + q * 4);
  bhA  = *(const float4*)(bh  + s * 64 + (2 * u_o) * 16 + q * 4);
  bhB  = *(const float4*)(bh  + s * 64 + (2 * u_o + 1) * 16 + q * 4);
  const size_t soff = ((size_t)((s * 2 + u_o) * 16 + gb * 2 + bt_oo) * 64 + lane) * 16;
  volatile u32x4* st0 = (volatile u32x4*)(p0 + soff);
  volatile u32x4* st1 = (volatile u32x4*)(p1 + soff);

  // per-wave load bases: fragment (i, bt) at base_i + bt*1024 (imm offset)
  const size_t oA0 = ((size_t)((wv * 4 + 0) * 16 + gb * 2) * 64 + lane) * 16;
  const size_t oA1 = ((size_t)((wv * 4 + 1) * 16 + gb * 2) * 64 + lane) * 16;
  const size_t oA2 = ((size_t)((wv * 4 + 2) * 16 + gb * 2) * 64 + lane) * 16;
  const size_t oA3 = ((size_t)((wv * 4 + 3) * 16 + gb * 2) * 64 + lane) * 16;

  // ---- sequential time steps
  for (int t = 0; t < SEQ; ++t) {
    const unsigned tauW = tag_of((unsigned)t);
    const int buf = t & 1;

    f32x4 acc[4][2];
#pragma unroll
    for (int rt = 0; rt < 4; ++rt)
#pragma unroll
      for (int bt = 0; bt < 2; ++bt) acc[rt][bt] = (f32x4){0.f, 0.f, 0.f, 0.f};

    if (t > 0) {
      const unsigned tauR = tag_of((unsigned)(t - 1));
      const unsigned char* rp = (t & 1) ? p0 : p1;     // plane of h_{t-1}
      const unsigned char* b0 = rp + oA0;
      const unsigned char* b1 = rp + oA1;
      const unsigned char* b2 = rp + oA2;
      const unsigned char* b3 = rp + oA3;
      u32x4 f0, f1, f2, f3, f4, f5, f6, f7;

      // ---- single-phase poll: full fragment loads + 32-tag verify, one RT
      for (;;) {
        asm volatile(
          "global_load_dwordx4 %0, %8, off sc0 sc1\n\t"
          "global_load_dwordx4 %1, %8, off offset:1024 sc0 sc1\n\t"
          "global_load_dwordx4 %2, %9, off sc0 sc1\n\t"
          "global_load_dwordx4 %3, %9, off offset:1024 sc0 sc1\n\t"
          "global_load_dwordx4 %4, %10, off sc0 sc1\n\t"
          "global_load_dwordx4 %5, %10, off offset:1024 sc0 sc1\n\t"
          "global_load_dwordx4 %6, %11, off sc0 sc1\n\t"
          "global_load_dwordx4 %7, %11, off offset:1024 sc0 sc1\n\t"
          "s_waitcnt vmcnt(0)"
          : "=&v"(f0), "=&v"(f1), "=&v"(f2), "=&v"(f3),
            "=&v"(f4), "=&v"(f5), "=&v"(f6), "=&v"(f7)
          : "v"(b0), "v"(b1), "v"(b2), "v"(b3)
          : "memory");
        __builtin_amdgcn_sched_barrier(0);
        unsigned vb = ((f0[0] ^ tauR) | (f0[1] ^ tauR) | (f0[2] ^ tauR) | (f0[3] ^ tauR) |
                       (f1[0] ^ tauR) | (f1[1] ^ tauR) | (f1[2] ^ tauR) | (f1[3] ^ tauR) |
                       (f2[0] ^ tauR) | (f2[1] ^ tauR) | (f2[2] ^ tauR) | (f2[3] ^ tauR) |
                       (f3[0] ^ tauR) | (f3[1] ^ tauR) | (f3[2] ^ tauR) | (f3[3] ^ tauR) |
                       (f4[0] ^ tauR) | (f4[1] ^ tauR) | (f4[2] ^ tauR) | (f4[3] ^ tauR) |
                       (f5[0] ^ tauR) | (f5[1] ^ tauR) | (f5[2] ^ tauR) | (f5[3] ^ tauR) |
                       (f6[0] ^ tauR) | (f6[1] ^ tauR) | (f6[2] ^ tauR) | (f6[3] ^ tauR) |
                       (f7[0] ^ tauR) | (f7[1] ^ tauR) | (f7[2] ^ tauR) | (f7[3] ^ tauR)) & 1u;
        if (__all((int)(vb == 0))) break;
        __builtin_amdgcn_s_sleep(1);
      }

      // ---- 64 MFMAs (hi+lo), fragment (i, bt) = f[2i+bt]
#define MSTEP(F, I, BT)                                                        \
      { bf16x8 a_ = __builtin_bit_cast(bf16x8, F);                             \
        acc[0][BT] = __builtin_amdgcn_mfma_f32_16x16x32_bf16(whi[I][0], a_, acc[0][BT], 0, 0, 0); \
        acc[0][BT] = __builtin_amdgcn_mfma_f32_16x16x32_bf16(wlo[I][0], a_, acc[0][BT], 0, 0, 0); \
        acc[1][BT] = __builtin_amdgcn_mfma_f32_16x16x32_bf16(whi[I][1], a_, acc[1][BT], 0, 0, 0); \
        acc[1][BT] = __builtin_amdgcn_mfma_f32_16x16x32_bf16(wlo[I][1], a_, acc[1][BT], 0, 0, 0); \
        acc[2][BT] = __builtin_amdgcn_mfma_f32_16x16x32_bf16(whi[I][2], a_, acc[2][BT], 0, 0, 0); \
        acc[2][BT] = __builtin_amdgcn_mfma_f32_16x16x32_bf16(wlo[I][2], a_, acc[2][BT], 0, 0, 0); \
        acc[3][BT] = __builtin_amdgcn_mfma_f32_16x16x32_bf16(whi[I][3], a_, acc[3][BT], 0, 0, 0); \
        acc[3][BT] = __builtin_amdgcn_mfma_f32_16x16x32_bf16(wlo[I][3], a_, acc[3][BT], 0, 0, 0); }
      MSTEP(f0, 0, 0) MSTEP(f1, 0, 1) MSTEP(f2, 1, 0) MSTEP(f3, 1, 1)
      MSTEP(f4, 2, 0) MSTEP(f5, 2, 1) MSTEP(f6, 3, 0) MSTEP(f7, 3, 1)
#undef MSTEP
    }

    // ---- write non-owned tiles to red[buf] (owner o=(rt&2)|bt keeps its own)
#pragma unroll
    for (int T = 0; T < 8; ++T) {
      const int rt = T >> 1, bt = T & 1;
      const int o = (rt & 2) | bt;
      if (o != wv) {
        const int slot = (wv > o) ? (wv - 1) : wv;
        red[buf][rt][bt][slot][lane] = acc[rt][bt];
      }
    }
    __syncthreads();   // the ONLY barrier in the step loop

    // ---- owner waves 0..3: reduce both tiles, epilogue, one 16B store
    if (wv < 4) {
      f32x4 sA = acc[2 * u_o][bt_oo];
      f32x4 sB = acc[2 * u_o + 1][bt_oo];
#pragma unroll
      for (int pr = 0; pr < 7; ++pr) {
        sA += red[buf][2 * u_o][bt_oo][pr][lane];
        sB += red[buf][2 * u_o + 1][bt_oo][pr][lane];
      }
      const float xb = xrow[t];
      const float a0 = fast_tanh(sA[0] + xb * whxA.x + bhA.x);
      const float a1 = fast_tanh(sA[1] + xb * whxA.y + bhA.y);
      const float a2 = fast_tanh(sA[2] + xb * whxA.z + bhA.z);
      const float a3 = fast_tanh(sA[3] + xb * whxA.w + bhA.w);
      const float c0 = fast_tanh(sB[0] + xb * whxB.x + bhB.x);
      const float c1 = fast_tanh(sB[1] + xb * whxB.y + bhB.y);
      const float c2 = fast_tanh(sB[2] + xb * whxB.z + bhB.z);
      const float c3 = fast_tanh(sB[3] + xb * whxB.w + bhB.w);
      u32x4 stv;
      stv[0] = (((unsigned)f2bf(a0) | ((unsigned)f2bf(a1) << 16)) & ~1u) | tauW;
      stv[1] = (((unsigned)f2bf(a2) | ((unsigned)f2bf(a3) << 16)) & ~1u) | tauW;
      stv[2] = (((unsigned)f2bf(c0) | ((unsigned)f2bf(c1) << 16)) & ~1u) | tauW;
      stv[3] = (((unsigned)f2bf(c2) | ((unsigned)f2bf(c3) << 16)) & ~1u) | tauW;
      if (t & 1) *st1 = stv; else *st0 = stv;   // fire-and-forget write-through
    }
  }

  // ---- final projection (one WG per batch-group): out = h_last @ Wph + bp
  if (s != 0) return;
  {
    const unsigned tauF = tag_of(255u);   // = 0
    u32x4 hf[4][2];
    for (;;) {
#pragma unroll
      for (int i = 0; i < 4; ++i)
#pragma unroll
        for (int bt = 0; bt < 2; ++bt)
          hf[i][bt] = *(const volatile u32x4*)
              (p1 + ((size_t)((wv * 4 + i) * 16 + gb * 2 + bt) * 64 + lane) * 16);
      unsigned bad = 0;
#pragma unroll
      for (int i = 0; i < 4; ++i)
#pragma unroll
        for (int bt = 0; bt < 2; ++bt)
#pragma unroll
          for (int w = 0; w < 4; ++w) bad |= (hf[i][bt][w] ^ tauF) & 1u;
      if (__all((int)(bad == 0))) break;
      __builtin_amdgcn_s_sleep(2);
    }

    float pr0[NCLS], pr1[NCLS];
#pragma unroll
    for (int c = 0; c < NCLS; ++c) { pr0[c] = 0.f; pr1[c] = 0.f; }
#pragma unroll
    for (int i = 0; i < 4; ++i) {
      const int ks = wv * 4 + i;
#pragma unroll
      for (int bt = 0; bt < 2; ++bt) {
#pragma unroll
        for (int w = 0; w < 4; ++w) {
          unsigned word = hf[i][bt][w];
#pragma unroll
          for (int h2 = 0; h2 < 2; ++h2) {
            int j = 2 * w + h2;
            int k = ks * 32 + 4 * q + (j & 3) + 16 * (j >> 2);
            float hv = bf2f((unsigned short)(h2 ? (word >> 16) : (word & 0xffffu)));
            const float* wrow = Wph + (size_t)k * NCLS;
#pragma unroll
            for (int c = 0; c < NCLS; ++c) {
              if (bt == 0) pr0[c] += hv * wrow[c];
              else         pr1[c] += hv * wrow[c];
            }
          }
        }
      }
    }
#pragma unroll
    for (int c = 0; c < NCLS; ++c) {
      pr0[c] += __shfl_xor(pr0[c], 16, 64); pr0[c] += __shfl_xor(pr0[c], 32, 64);
      pr1[c] += __shfl_xor(pr1[c], 16, 64); pr1[c] += __shfl_xor(pr1[c], 32, 64);
    }
    float* projl = (float*)&red[0][0][0][0][0];   // reuse LDS: [8 wv][2 bt][16 b][10 c]
    if (q == 0) {
#pragma unroll
      for (int c = 0; c < NCLS; ++c) {
        projl[((wv * 2 + 0) * 16 + l15) * NCLS + c] = pr0[c];
        projl[((wv * 2 + 1) * 16 + l15) * NCLS + c] = pr1[c];
      }
    }
    __syncthreads();
    if (tid < 32 * NCLS) {
      int bl = tid / NCLS, c = tid - bl * NCLS;
      float sum = bp[c];
#pragma unroll
      for (int w = 0; w < 8; ++w)
        sum += projl[((w * 2 + (bl >> 4)) * 16 + (bl & 15)) * NCLS + c];
      out[(size_t)(gb * 32 + bl) * NCLS + c] = sum;
    }
  }
}

extern "C" void kernel_launch(void* const* d_in, const int* in_sizes, int n_in,
                              void* d_out, int out_size, void* d_ws, size_t ws_size,
                              hipStream_t stream) {
  const float* x   = (const float*)d_in[0];
  const float* Whx = (const float*)d_in[1];
  const float* Whh = (const float*)d_in[2];
  const float* Wph = (const float*)d_in[3];
  const float* bh  = (const float*)d_in[4];
  const float* bp  = (const float*)d_in[5];

  // no memset: tags self-validate against poison / stale replay data
  hipLaunchKernelGGL(rnn_onebar, dim3(NWG), dim3(THREADS), 0, stream,
                     x, Whx, Whh, Wph, bh, bp,
                     (float*)d_out, (unsigned char*)d_ws);
}